// Round 1
// baseline (76.506 us; speedup 1.0000x reference)
//
#include <hip/hip_runtime.h>
#include <stdint.h>

#define SEQ   2048
#define BITS  256
#define HEADS 8
#define NPOS  4
#define MAXD  8
#define NBPN  12

typedef unsigned long long u64;
typedef unsigned int       u32;
typedef unsigned short     u16;

// ---- workspace layout (bytes) ----
#define OFF_TBL    0                         // 512 u64   (4096 B)
#define OFF_PACKED 4096                      // SEQ*4 u64 (65536 B)
#define OFF_AQ     (4096 + 65536)            // SEQ*HEADS u16 (32768 B)
#define OFF_AK     (4096 + 65536 + 32768)    // SEQ*HEADS u16 (32768 B)
#define OFF_AR     (4096 + 65536 + 65536)    // 9*HEADS u16 (144 B)

// LDS table replication: 4 copies, word stride 1028 (1028 & 31 == 4 -> each
// copy's bank mapping rotated by 4 banks). Lane uses copy (lane & 3), so the
// 64 lanes split into 4 groups of 16 hitting rotated bank sets. Rationale:
// bank = (addr>>5)&31 and only a head's k-bits vary across lanes, giving
// ~2^2.5 distinct banks per 64 lanes (avg ~11-way conflict) without this.
#define TBL_STRIDE 1028
#define NCOPY      4

// Fused prep kernel (~2-3 us incl. launch):
//   [0, 2048)    : pack tokens via ballot   (SEQ*BITS bits)
//   [2048, 2176) : pack table via ballot    (HEADS*4096 bits)
//   [2176, 2240) : Aq/Ak/Ar address parts
__global__ __launch_bounds__(256) void prep_kernel(
        const int* __restrict__ tokens, const int* __restrict__ head_idx,
        const float* __restrict__ table,
        u64* __restrict__ tblbits, u64* __restrict__ packed,
        u16* __restrict__ Aq, u16* __restrict__ Ak, u16* __restrict__ Ar) {
    const int bid = blockIdx.x, tid = threadIdx.x;
    if (bid < 2048) {
        int t = bid * 256 + tid;
        u64 m = __ballot(tokens[t] & 1);
        if ((tid & 63) == 0) packed[t >> 6] = m;
    } else if (bid < 2048 + 128) {
        int t = (bid - 2048) * 256 + tid;
        u64 m = __ballot(table[t] != 0.0f);
        if ((tid & 63) == 0) tblbits[t >> 6] = m;
    } else {
        int t = (bid - 2176) * 256 + tid;        // 0..16383
        int s = t >> 3, h = t & 7;
        const int* hi  = head_idx + h * NBPN;
        const int* tok = tokens + s * BITS;
        int aq = 0, ak = 0;
        #pragma unroll
        for (int k = 0; k < NBPN; ++k) {
            int idx = hi[k];
            if (idx < BITS)          aq += tok[idx] << k;
            else if (idx < 2 * BITS) ak += tok[idx - BITS] << k;
        }
        Aq[t] = (u16)aq;
        Ak[t] = (u16)ak;
        if (t < (MAXD + 1) * HEADS) {            // 72 threads also fill Ar
            int d = t / HEADS, hh = t % HEADS;
            const int* hi2 = head_idx + hh * NBPN;
            int ar = 0;
            #pragma unroll
            for (int k = 0; k < NBPN; ++k) {
                int idx = hi2[k];
                if (idx >= 2 * BITS) ar += ((d >> (idx - 2 * BITS)) & 1) << k;
            }
            Ar[t] = (u16)ar;
        }
    }
}

__device__ inline u64 shfl_down_u64(u64 x, int o) {
    u32 lo = (u32)x, hi = (u32)(x >> 32);
    lo = __shfl_down(lo, o, 64);
    hi = __shfl_down(hi, o, 64);
    return ((u64)hi << 32) | lo;
}

// One row per block, 2 waves (R4 structure). Near-diagonal (dist<8) peeled to
// threads 0..7; main loop branch-free with register a8 base + next-iteration
// prefetch of Ak/packed. This round: 4x bank-rotated LDS table replication
// (targets ~11-way avg bank conflicts on the 8 random table lookups/pair) and
// u32 argmax key ((votes+1)<<12 | (2047-j), first-max = smallest j on ties).
__global__ __launch_bounds__(128) void row_kernel(
        const u64* __restrict__ tblbits, const u64* __restrict__ packed,
        const u16* __restrict__ Aq, const u16* __restrict__ Ak,
        const u16* __restrict__ Ar, float* __restrict__ out) {

    __shared__ u32 tbl[NCOPY * TBL_STRIDE];  // 16448 B: 4 rotated copies
    __shared__ u16 aqar[MAXD + 1][HEADS];
    __shared__ u64 p_acc[2][4];
    __shared__ int p_inc[2];
    __shared__ u32 p_key[2];

    const int i   = blockIdx.x;
    const int tid = threadIdx.x;

    // stage table: read 32B/thread, write to 4 rotated copies (uint4-aligned:
    // TBL_STRIDE*4 = 4112 B is 16B-aligned)
    {
        const uint4* tb4 = (const uint4*)tblbits;
        uint4 v0 = tb4[tid];
        uint4 v1 = tb4[tid + 128];
        #pragma unroll
        for (int c = 0; c < NCOPY; ++c) {
            uint4* dst = (uint4*)(tbl + c * TBL_STRIDE);
            dst[tid]       = v0;
            dst[tid + 128] = v1;
        }
    }
    if (tid < (MAXD + 1) * HEADS) {
        int h = tid & 7;
        aqar[tid >> 3][h] = (u16)(Aq[i * HEADS + h] + Ar[tid]);
    }
    __syncthreads();

    const u32* tblc = tbl + (tid & (NCOPY - 1)) * TBL_STRIDE;

    u32 a8[8];                             // dist>=8 bases in registers
    #pragma unroll
    for (int h = 0; h < 8; ++h) a8[h] = aqar[MAXD][h];

    u64 acc0 = 0, acc1 = 0, acc2 = 0, acc3 = 0;
    int inc = 0;
    u32 bestkey = 0;

    // ---- peel: dist = tid in [0,8), j = i - dist ----
    if (tid < MAXD) {
        int j = i - tid;
        if (j >= 0) {
            const uint4 akv = *(const uint4*)(Ak + j * HEADS);
            int votes = 0;
            #pragma unroll
            for (int h = 0; h < 8; ++h) {
                u32 ak_h = ((&akv.x)[h >> 1] >> ((h & 1) * 16)) & 0xFFFFu;
                u32 addr = (u32)aqar[tid][h] + ak_h;
                votes += (int)((tblc[(h << 7) + (addr >> 5)] >> (addr & 31)) & 1u);
            }
            int att = (votes >= HEADS / 2) ? 1 : 0;
            u64 m = (u64)0 - (u64)att;
            const ulonglong2* pj = (const ulonglong2*)(packed + j * 4);
            ulonglong2 pA = pj[0], pB = pj[1];
            acc0 ^= pA.x & m; acc1 ^= pA.y & m;
            acc2 ^= pB.x & m; acc3 ^= pB.y & m;
            inc += att;
            u32 key = ((u32)(votes + 1) << 12) | (u32)(2047 - j);
            if (key > bestkey) bestkey = key;
        }
    }

    // ---- main: j <= i - 8, branch-free base, prefetched ----
    const int ilim = i - MAXD;
    int j = tid;
    uint4 akv; ulonglong2 pA, pB;
    if (j <= ilim) {
        akv = *(const uint4*)(Ak + j * HEADS);
        const ulonglong2* pj = (const ulonglong2*)(packed + j * 4);
        pA = pj[0]; pB = pj[1];
    }
    while (j <= ilim) {
        const int jn = j + 128;
        uint4 akv_n; ulonglong2 pA_n, pB_n;
        if (jn <= ilim) {                  // prefetch next tile
            akv_n = *(const uint4*)(Ak + jn * HEADS);
            const ulonglong2* pjn = (const ulonglong2*)(packed + jn * 4);
            pA_n = pjn[0]; pB_n = pjn[1];
        }
        int votes = 0;
        #pragma unroll
        for (int h = 0; h < 8; ++h) {
            u32 ak_h = ((&akv.x)[h >> 1] >> ((h & 1) * 16)) & 0xFFFFu;
            u32 addr = a8[h] + ak_h;       // < 4096 (disjoint bit masks)
            votes += (int)((tblc[(h << 7) + (addr >> 5)] >> (addr & 31)) & 1u);
        }
        int att = (votes >= HEADS / 2) ? 1 : 0;
        u64 m = (u64)0 - (u64)att;
        acc0 ^= pA.x & m; acc1 ^= pA.y & m;
        acc2 ^= pB.x & m; acc3 ^= pB.y & m;
        inc += att;
        u32 key = ((u32)(votes + 1) << 12) | (u32)(2047 - j);
        if (key > bestkey) bestkey = key;
        j = jn; akv = akv_n; pA = pA_n; pB = pB_n;
    }

    #pragma unroll
    for (int o = 32; o > 0; o >>= 1) {
        acc0 ^= shfl_down_u64(acc0, o);
        acc1 ^= shfl_down_u64(acc1, o);
        acc2 ^= shfl_down_u64(acc2, o);
        acc3 ^= shfl_down_u64(acc3, o);
        inc  += __shfl_down(inc, o, 64);
        u32 k2 = __shfl_down(bestkey, o, 64);
        if (k2 > bestkey) bestkey = k2;
    }
    int wave = tid >> 6;
    if ((tid & 63) == 0) {
        p_acc[wave][0] = acc0; p_acc[wave][1] = acc1;
        p_acc[wave][2] = acc2; p_acc[wave][3] = acc3;
        p_inc[wave] = inc; p_key[wave] = bestkey;
    }
    __syncthreads();

    u64 f0 = p_acc[0][0] ^ p_acc[1][0];
    u64 f1 = p_acc[0][1] ^ p_acc[1][1];
    u64 f2 = p_acc[0][2] ^ p_acc[1][2];
    u64 f3 = p_acc[0][3] ^ p_acc[1][3];
    int finc = p_inc[0] + p_inc[1];
    u32 fk = (p_key[0] > p_key[1]) ? p_key[0] : p_key[1];

    int b0   = tid * 2;                    // 2 output bits per thread
    int wsel = tid >> 5;
    u64 word;
    if (finc > 0) {
        word = (wsel < 2) ? (wsel == 0 ? f0 : f1) : (wsel == 2 ? f2 : f3);
    } else {
        int bestj = 2047 - (int)(fk & 0xFFFu);
        word = packed[bestj * 4 + wsel];
    }
    int sh = b0 & 63;
    float2 o2 = make_float2((float)((word >> sh) & 1ull),
                            (float)((word >> (sh + 1)) & 1ull));
    *(float2*)(out + i * BITS + b0) = o2;
}

extern "C" void kernel_launch(void* const* d_in, const int* in_sizes, int n_in,
                              void* d_out, int out_size, void* d_ws, size_t ws_size,
                              hipStream_t stream) {
    const int*   tokens   = (const int*)d_in[0];
    const int*   head_idx = (const int*)d_in[1];
    const float* table    = (const float*)d_in[2];
    float*       out      = (float*)d_out;
    char*        ws       = (char*)d_ws;

    u64* tblbits = (u64*)(ws + OFF_TBL);
    u64* packed  = (u64*)(ws + OFF_PACKED);
    u16* Aq      = (u16*)(ws + OFF_AQ);
    u16* Ak      = (u16*)(ws + OFF_AK);
    u16* Ar      = (u16*)(ws + OFF_AR);

    prep_kernel<<<2240, 256, 0, stream>>>(tokens, head_idx, table,
                                          tblbits, packed, Aq, Ak, Ar);
    row_kernel <<<SEQ, 128, 0, stream>>>(tblbits, packed, Aq, Ak, Ar, out);
}

// Round 2
// 74.168 us; speedup vs baseline: 1.0315x; 1.0315x over previous
//
#include <hip/hip_runtime.h>
#include <stdint.h>

#define SEQ   2048
#define BITS  256
#define HEADS 8
#define NPOS  4
#define MAXD  8
#define NBPN  12

typedef unsigned long long u64;
typedef unsigned int       u32;
typedef unsigned short     u16;

// ---- workspace layout (bytes) ----
#define OFF_TBL    0                         // 512 u64   (4096 B)
#define OFF_PACKED 4096                      // SEQ*4 u64 (65536 B)
#define OFF_AQ     (4096 + 65536)            // SEQ*HEADS u16 (32768 B)
#define OFF_AK     (4096 + 65536 + 32768)    // SEQ*HEADS u16 (32768 B)
#define OFF_AR     (4096 + 65536 + 65536)    // 9*HEADS u16 (144 B)

// Fused prep kernel (~2-3 us incl. launch):
//   [0, 2048)    : pack tokens via ballot   (SEQ*BITS bits)
//   [2048, 2176) : pack table via ballot    (HEADS*4096 bits)
//   [2176, 2240) : Aq/Ak/Ar address parts
__global__ __launch_bounds__(256) void prep_kernel(
        const int* __restrict__ tokens, const int* __restrict__ head_idx,
        const float* __restrict__ table,
        u64* __restrict__ tblbits, u64* __restrict__ packed,
        u16* __restrict__ Aq, u16* __restrict__ Ak, u16* __restrict__ Ar) {
    const int bid = blockIdx.x, tid = threadIdx.x;
    if (bid < 2048) {
        int t = bid * 256 + tid;
        u64 m = __ballot(tokens[t] & 1);
        if ((tid & 63) == 0) packed[t >> 6] = m;
    } else if (bid < 2048 + 128) {
        int t = (bid - 2048) * 256 + tid;
        u64 m = __ballot(table[t] != 0.0f);
        if ((tid & 63) == 0) tblbits[t >> 6] = m;
    } else {
        int t = (bid - 2176) * 256 + tid;        // 0..16383
        int s = t >> 3, h = t & 7;
        const int* hi  = head_idx + h * NBPN;
        const int* tok = tokens + s * BITS;
        int aq = 0, ak = 0;
        #pragma unroll
        for (int k = 0; k < NBPN; ++k) {
            int idx = hi[k];
            if (idx < BITS)          aq += tok[idx] << k;
            else if (idx < 2 * BITS) ak += tok[idx - BITS] << k;
        }
        Aq[t] = (u16)aq;
        Ak[t] = (u16)ak;
        if (t < (MAXD + 1) * HEADS) {            // 72 threads also fill Ar
            int d = t / HEADS, hh = t % HEADS;
            const int* hi2 = head_idx + hh * NBPN;
            int ar = 0;
            #pragma unroll
            for (int k = 0; k < NBPN; ++k) {
                int idx = hi2[k];
                if (idx >= 2 * BITS) ar += ((d >> (idx - 2 * BITS)) & 1) << k;
            }
            Ar[t] = (u16)ar;
        }
    }
}

__device__ inline u64 shfl_down_u64(u64 x, int o) {
    u32 lo = (u32)x, hi = (u32)(x >> 32);
    lo = __shfl_down(lo, o, 64);
    hi = __shfl_down(hi, o, 64);
    return ((u64)hi << 32) | lo;
}

// One row per block, 2 waves (R4 structure). Near-diagonal (dist<8) peeled to
// threads 0..7. This round: single 4KB table copy (R1's 4x bank-rotation was
// neutral-negative: real collision depth is ~2-way = free per m136; revert),
// main loop unrolled x2 (j and j+128 per iteration, tile stride 256) to halve
// the deepest row's serial iteration count 16->8 and double in-flight
// LDS/global requests. u32 argmax key: (votes<<12)|(2047-j); max == first
// argmax (tie -> smallest j). Init 0 is safe: j=0 (or the peel's j=i for
// row 0) always produces key >= 2047-j > 0 for some pair.
__global__ __launch_bounds__(128) void row_kernel(
        const u64* __restrict__ tblbits, const u64* __restrict__ packed,
        const u16* __restrict__ Aq, const u16* __restrict__ Ak,
        const u16* __restrict__ Ar, float* __restrict__ out) {

    __shared__ u32 tbl[HEADS * 128];       // 4 KB table bitmask (u32 words)
    __shared__ u16 aqar[MAXD + 1][HEADS];
    __shared__ u64 p_acc[2][4];
    __shared__ int p_inc[2];
    __shared__ u32 p_key[2];

    const int i   = blockIdx.x;
    const int tid = threadIdx.x;

    // stage table via 2x dwordx4 -> 2x ds_write_b128 per thread
    {
        const uint4* tb4 = (const uint4*)tblbits;
        uint4* tl4 = (uint4*)tbl;
        tl4[tid]       = tb4[tid];
        tl4[tid + 128] = tb4[tid + 128];
    }
    if (tid < (MAXD + 1) * HEADS) {
        int h = tid & 7;
        aqar[tid >> 3][h] = (u16)(Aq[i * HEADS + h] + Ar[tid]);
    }
    __syncthreads();

    u32 a8[8];                             // dist>=8 bases in registers
    #pragma unroll
    for (int h = 0; h < 8; ++h) a8[h] = aqar[MAXD][h];

    u64 acc0 = 0, acc1 = 0, acc2 = 0, acc3 = 0;
    int inc = 0;
    u32 bestkey = 0;

    // ---- peel: dist = tid in [0,8), j = i - dist ----
    if (tid < MAXD) {
        int j = i - tid;
        if (j >= 0) {
            const uint4 akv = *(const uint4*)(Ak + j * HEADS);
            int votes = 0;
            #pragma unroll
            for (int h = 0; h < 8; ++h) {
                u32 ak_h = ((&akv.x)[h >> 1] >> ((h & 1) * 16)) & 0xFFFFu;
                u32 addr = (u32)aqar[tid][h] + ak_h;
                votes += (int)((tbl[(h << 7) + (addr >> 5)] >> (addr & 31)) & 1u);
            }
            int att = (votes >= HEADS / 2) ? 1 : 0;
            u64 m = (u64)0 - (u64)att;
            const ulonglong2* pj = (const ulonglong2*)(packed + j * 4);
            ulonglong2 pA = pj[0], pB = pj[1];
            acc0 ^= pA.x & m; acc1 ^= pA.y & m;
            acc2 ^= pB.x & m; acc3 ^= pB.y & m;
            inc += att;
            u32 key = ((u32)votes << 12) | (u32)(2047 - j);
            if (key > bestkey) bestkey = key;
        }
    }

    // ---- main: j <= i - 8, unrolled x2 (slots A=j, B=j+128), branch-free
    //      base, cross-tile prefetch of both slots ----
    const int ilim = i - MAXD;
    int jA = tid, jB = tid + 128;
    uint4 akA, akB; ulonglong2 a0, a1, b0, b1;
    if (jA <= ilim) {
        akA = *(const uint4*)(Ak + jA * HEADS);
        const ulonglong2* p = (const ulonglong2*)(packed + jA * 4);
        a0 = p[0]; a1 = p[1];
    }
    if (jB <= ilim) {
        akB = *(const uint4*)(Ak + jB * HEADS);
        const ulonglong2* p = (const ulonglong2*)(packed + jB * 4);
        b0 = p[0]; b1 = p[1];
    }
    while (jA <= ilim) {
        const int jAn = jA + 256, jBn = jB + 256;
        uint4 akA_n, akB_n; ulonglong2 a0_n, a1_n, b0_n, b1_n;
        if (jAn <= ilim) {                 // prefetch next tile, slot A
            akA_n = *(const uint4*)(Ak + jAn * HEADS);
            const ulonglong2* p = (const ulonglong2*)(packed + jAn * 4);
            a0_n = p[0]; a1_n = p[1];
        }
        if (jBn <= ilim) {                 // prefetch next tile, slot B
            akB_n = *(const uint4*)(Ak + jBn * HEADS);
            const ulonglong2* p = (const ulonglong2*)(packed + jBn * 4);
            b0_n = p[0]; b1_n = p[1];
        }
        // slot A (always valid inside loop)
        {
            int votes = 0;
            #pragma unroll
            for (int h = 0; h < 8; ++h) {
                u32 ak_h = ((&akA.x)[h >> 1] >> ((h & 1) * 16)) & 0xFFFFu;
                u32 addr = a8[h] + ak_h;   // < 4096 (disjoint bit masks)
                votes += (int)((tbl[(h << 7) + (addr >> 5)] >> (addr & 31)) & 1u);
            }
            int att = (votes >= HEADS / 2) ? 1 : 0;
            u64 m = (u64)0 - (u64)att;
            acc0 ^= a0.x & m; acc1 ^= a0.y & m;
            acc2 ^= a1.x & m; acc3 ^= a1.y & m;
            inc += att;
            u32 key = ((u32)votes << 12) | (u32)(2047 - jA);
            if (key > bestkey) bestkey = key;
        }
        // slot B (invalid only in the final partial tile)
        if (jB <= ilim) {
            int votes = 0;
            #pragma unroll
            for (int h = 0; h < 8; ++h) {
                u32 ak_h = ((&akB.x)[h >> 1] >> ((h & 1) * 16)) & 0xFFFFu;
                u32 addr = a8[h] + ak_h;
                votes += (int)((tbl[(h << 7) + (addr >> 5)] >> (addr & 31)) & 1u);
            }
            int att = (votes >= HEADS / 2) ? 1 : 0;
            u64 m = (u64)0 - (u64)att;
            acc0 ^= b0.x & m; acc1 ^= b0.y & m;
            acc2 ^= b1.x & m; acc3 ^= b1.y & m;
            inc += att;
            u32 key = ((u32)votes << 12) | (u32)(2047 - jB);
            if (key > bestkey) bestkey = key;
        }
        jA = jAn; jB = jBn;
        akA = akA_n; akB = akB_n;
        a0 = a0_n; a1 = a1_n; b0 = b0_n; b1 = b1_n;
    }

    #pragma unroll
    for (int o = 32; o > 0; o >>= 1) {
        acc0 ^= shfl_down_u64(acc0, o);
        acc1 ^= shfl_down_u64(acc1, o);
        acc2 ^= shfl_down_u64(acc2, o);
        acc3 ^= shfl_down_u64(acc3, o);
        inc  += __shfl_down(inc, o, 64);
        u32 k2 = __shfl_down(bestkey, o, 64);
        if (k2 > bestkey) bestkey = k2;
    }
    int wave = tid >> 6;
    if ((tid & 63) == 0) {
        p_acc[wave][0] = acc0; p_acc[wave][1] = acc1;
        p_acc[wave][2] = acc2; p_acc[wave][3] = acc3;
        p_inc[wave] = inc; p_key[wave] = bestkey;
    }
    __syncthreads();

    u64 f0 = p_acc[0][0] ^ p_acc[1][0];
    u64 f1 = p_acc[0][1] ^ p_acc[1][1];
    u64 f2 = p_acc[0][2] ^ p_acc[1][2];
    u64 f3 = p_acc[0][3] ^ p_acc[1][3];
    int finc = p_inc[0] + p_inc[1];
    u32 fk = (p_key[0] > p_key[1]) ? p_key[0] : p_key[1];

    int b0o  = tid * 2;                    // 2 output bits per thread
    int wsel = tid >> 5;
    u64 word;
    if (finc > 0) {
        word = (wsel < 2) ? (wsel == 0 ? f0 : f1) : (wsel == 2 ? f2 : f3);
    } else {
        int bestj = 2047 - (int)(fk & 0xFFFu);
        word = packed[bestj * 4 + wsel];
    }
    int sh = b0o & 63;
    float2 o2 = make_float2((float)((word >> sh) & 1ull),
                            (float)((word >> (sh + 1)) & 1ull));
    *(float2*)(out + i * BITS + b0o) = o2;
}

extern "C" void kernel_launch(void* const* d_in, const int* in_sizes, int n_in,
                              void* d_out, int out_size, void* d_ws, size_t ws_size,
                              hipStream_t stream) {
    const int*   tokens   = (const int*)d_in[0];
    const int*   head_idx = (const int*)d_in[1];
    const float* table    = (const float*)d_in[2];
    float*       out      = (float*)d_out;
    char*        ws       = (char*)d_ws;

    u64* tblbits = (u64*)(ws + OFF_TBL);
    u64* packed  = (u64*)(ws + OFF_PACKED);
    u16* Aq      = (u16*)(ws + OFF_AQ);
    u16* Ak      = (u16*)(ws + OFF_AK);
    u16* Ar      = (u16*)(ws + OFF_AR);

    prep_kernel<<<2240, 256, 0, stream>>>(tokens, head_idx, table,
                                          tblbits, packed, Aq, Ak, Ar);
    row_kernel <<<SEQ, 128, 0, stream>>>(tblbits, packed, Aq, Ak, Ar, out);
}